// Round 1
// baseline (96734.381 us; speedup 1.0000x reference)
//
#include <hip/hip_runtime.h>
#include <hip/hip_cooperative_groups.h>

namespace cg = cooperative_groups;

#define TT 1024
#define BB 64
#define IN_ 512
#define HID_ 512
#define KTOT 1024
#define SLICE (BB * HID_)  // 32768 floats, one [t] slice of out / one Xt slice

__device__ __forceinline__ float sigmoid_fast(float x) {
  return 1.0f / (1.0f + __expf(-x));
}

__device__ __forceinline__ float tanh_fast(float x) {
  float ax = fabsf(x);
  float e = __expf(2.0f * ax);          // >= 1, inf-safe
  float r = 1.0f - 2.0f / (e + 1.0f);   // in [0,1)
  return copysignf(r, x);
}

// Build masked, transposed, gate-interleaved weights: W4[k][j][g]
//   k <  512 : masked W_x[g][j][k]   (threshold = thresholds[j][g])
//   k >= 512 : masked W_h[g][j][k-512] (threshold = thresholds[j][4+g])
__global__ void prep_weights(const float* __restrict__ Wx,
                             const float* __restrict__ Wh,
                             const float* __restrict__ thr,
                             float* __restrict__ W4) {
  int idx = blockIdx.x * 256 + threadIdx.x;  // = k*512 + j
  int k = idx >> 9;
  int j = idx & 511;
  float4 w4;
  float* wp = reinterpret_cast<float*>(&w4);
#pragma unroll
  for (int g = 0; g < 4; ++g) {
    float w, th;
    if (k < IN_) {
      w = Wx[(g * HID_ + j) * IN_ + k];
      th = thr[j * 8 + g];
    } else {
      w = Wh[(g * HID_ + j) * HID_ + (k - IN_)];
      th = thr[j * 8 + 4 + g];
    }
    float m = ((fabsf(w) - th) >= 0.0f) ? 1.0f : 0.0f;  // unit_step(|w|-thr)
    wp[g] = w * m;
  }
  reinterpret_cast<float4*>(W4)[idx] = w4;
}

// Transpose X[t][b][k] -> Xt[t][k][b]. Xt[t] is stored in out slice (t+1);
// Xt[T-1] goes to xlast (ws). Step t of the recurrent kernel reads slice t+1
// and writes H_t into slice t, so reads always precede any overwrite.
__global__ void transpose_x(const float* __restrict__ X,
                            float* __restrict__ out,
                            float* __restrict__ xlast) {
  __shared__ float tile[64][129];
  int t = blockIdx.x >> 2;
  int k0 = (blockIdx.x & 3) * 128;
  const float* src = X + (size_t)t * (BB * IN_) + k0;
#pragma unroll
  for (int j = 0; j < 8; ++j) {
    int f = threadIdx.x + j * 256;   // float4 index in 64x128 tile
    int b = f >> 5;                  // 32 float4 per row
    int m = (f & 31) * 4;
    float4 v = *reinterpret_cast<const float4*>(src + b * IN_ + m);
    tile[b][m + 0] = v.x; tile[b][m + 1] = v.y;
    tile[b][m + 2] = v.z; tile[b][m + 3] = v.w;
  }
  __syncthreads();
  float* dst = (t < TT - 1) ? (out + (size_t)(t + 1) * SLICE) : xlast;
  int b = threadIdx.x & 63;
  int ks = threadIdx.x >> 6;
#pragma unroll
  for (int u = 0; u < 32; ++u) {
    int kk = ks * 32 + u;
    dst[(k0 + kk) * BB + b] = tile[b][kk];  // lanes b consecutive: coalesced
  }
}

// Persistent cooperative LSTM. 256 blocks x 512 threads.
// Block owns h-pair {2*blk, 2*blk+1}; thread = (b = tid&63, ksub = tid>>6).
// Each thread accumulates 2h x 4g partial dots over its 128-wide k window,
// LDS-reduces across the 8 ksub, then threads 0..127 do the pointwise LSTM
// cell (C held in registers across all 1024 steps).
__global__ void __launch_bounds__(512) lstm_rec(
    const float* __restrict__ W4, const float* __restrict__ bias,
    const float* __restrict__ h0p, const float* __restrict__ c0p,
    float* __restrict__ Hb0, float* __restrict__ Hb1,
    const float* __restrict__ xlast, float* __restrict__ out) {
  cg::grid_group grid = cg::this_grid();
  __shared__ float red[8][64][9];  // pad 9: conflict-free strided reads
  const int tid = threadIdx.x;
  const int blk = blockIdx.x;
  const int b = tid & 63;
  const int ksub = __builtin_amdgcn_readfirstlane(tid >> 6);  // wave-uniform
  const int h0c = blk * 2;

  // Init: H_{-1} = h0 into Hb0 in [h][b] layout; C from c0.
  float C = 0.0f;
  if (tid < 128) {
    int hh = h0c + (tid >> 6);
    Hb0[hh * BB + b] = h0p[b * HID_ + hh];
    C = c0p[b * HID_ + hh];
  }
  grid.sync();

  for (int t = 0; t < TT; ++t) {
    const float* Hprev = (t & 1) ? Hb1 : Hb0;
    float* Hnext = (t & 1) ? Hb0 : Hb1;
    const float* Xs = (t < TT - 1) ? (out + (size_t)(t + 1) * SLICE) : xlast;
    const int k0 = ksub * 128;
    const float* Abase = (ksub < 4) ? (Xs + k0 * BB + b)
                                    : (Hprev + (k0 - IN_) * BB + b);
    const float* Wp = W4 + k0 * (HID_ * 4) + h0c * 4;  // scalar-provable

    float4 acc0 = make_float4(0.f, 0.f, 0.f, 0.f);  // h0: gates i,f,o,c
    float4 acc1 = make_float4(0.f, 0.f, 0.f, 0.f);  // h1
#pragma unroll 4
    for (int i = 0; i < 128; ++i) {
      float a = Abase[i * BB];  // lane-coalesced [k][b] load
      float4 w0 = *reinterpret_cast<const float4*>(Wp + i * (HID_ * 4));
      float4 w1 = *reinterpret_cast<const float4*>(Wp + i * (HID_ * 4) + 4);
      acc0.x = fmaf(a, w0.x, acc0.x);
      acc0.y = fmaf(a, w0.y, acc0.y);
      acc0.z = fmaf(a, w0.z, acc0.z);
      acc0.w = fmaf(a, w0.w, acc0.w);
      acc1.x = fmaf(a, w1.x, acc1.x);
      acc1.y = fmaf(a, w1.y, acc1.y);
      acc1.z = fmaf(a, w1.z, acc1.z);
      acc1.w = fmaf(a, w1.w, acc1.w);
    }
    float* rp = &red[ksub][b][0];
    rp[0] = acc0.x; rp[1] = acc0.y; rp[2] = acc0.z; rp[3] = acc0.w;
    rp[4] = acc1.x; rp[5] = acc1.y; rp[6] = acc1.z; rp[7] = acc1.w;
    __syncthreads();

    if (tid < 128) {
      int hsub = tid >> 6;
      int hh = h0c + hsub;
      float gs[4];
#pragma unroll
      for (int gg = 0; gg < 4; ++gg) {
        float s = bias[gg * HID_ + hh];
#pragma unroll
        for (int ks = 0; ks < 8; ++ks) s += red[ks][b][hsub * 4 + gg];
        gs[gg] = s;
      }
      float I = sigmoid_fast(gs[0]);
      float F = sigmoid_fast(gs[1]);
      float O = sigmoid_fast(gs[2]);
      float Ctl = tanh_fast(gs[3]);
      C = F * C + I * Ctl;
      float H = O * tanh_fast(C);
      out[(size_t)t * SLICE + b * HID_ + hh] = H;  // final output
      Hnext[hh * BB + b] = H;                      // [h][b] for next step
    }
    __threadfence();
    grid.sync();
  }
}

extern "C" void kernel_launch(void* const* d_in, const int* in_sizes, int n_in,
                              void* d_out, int out_size, void* d_ws, size_t ws_size,
                              hipStream_t stream) {
  (void)in_sizes; (void)n_in; (void)out_size; (void)ws_size;
  const float* X    = (const float*)d_in[0];
  const float* Wx   = (const float*)d_in[1];
  const float* Wh   = (const float*)d_in[2];
  const float* bias = (const float*)d_in[3];
  const float* thr  = (const float*)d_in[4];
  const float* h0p  = (const float*)d_in[5];
  const float* c0p  = (const float*)d_in[6];
  float* out = (float*)d_out;

  // ws layout (floats): W4 [1024][512][4] | Hb0 | Hb1 | xlast  (~8.8 MB)
  float* W4 = (float*)d_ws;
  float* Hb0 = W4 + (size_t)KTOT * HID_ * 4;
  float* Hb1 = Hb0 + SLICE;
  float* xlast = Hb1 + SLICE;

  prep_weights<<<(KTOT * HID_) / 256, 256, 0, stream>>>(Wx, Wh, thr, W4);
  transpose_x<<<TT * 4, 256, 0, stream>>>(X, out, xlast);

  void* args[] = {&W4, &bias, &h0p, &c0p, &Hb0, &Hb1, &xlast, &out};
  hipLaunchCooperativeKernel(reinterpret_cast<void*>(lstm_rec),
                             dim3(256), dim3(512), args, 0, stream);
}

// Round 2
// 86333.948 us; speedup vs baseline: 1.1205x; 1.1205x over previous
//
#include <hip/hip_runtime.h>
#include <hip/hip_cooperative_groups.h>

namespace cg = cooperative_groups;

#define TT 1024
#define BB 64
#define IN_ 512
#define HID_ 512
#define KTOT 1024
#define SLICE (BB * HID_)  // 32768 floats, one [t] slice of out / one Xt slice

typedef float v2f __attribute__((ext_vector_type(2)));

__device__ __forceinline__ float sigmoid_fast(float x) {
  return 1.0f / (1.0f + __expf(-x));
}

__device__ __forceinline__ float tanh_fast(float x) {
  float ax = fabsf(x);
  float e = __expf(2.0f * ax);          // >= 1, inf-safe
  float r = 1.0f - 2.0f / (e + 1.0f);   // in [0,1)
  return copysignf(r, x);
}

// Build masked, transposed, gate-interleaved weights: W4[k][j][g]
//   k <  512 : masked W_x[g][j][k]   (threshold = thresholds[j][g])
//   k >= 512 : masked W_h[g][j][k-512] (threshold = thresholds[j][4+g])
__global__ void prep_weights(const float* __restrict__ Wx,
                             const float* __restrict__ Wh,
                             const float* __restrict__ thr,
                             float* __restrict__ W4) {
  int idx = blockIdx.x * 256 + threadIdx.x;  // = k*512 + j
  int k = idx >> 9;
  int j = idx & 511;
  float4 w4;
  float* wp = reinterpret_cast<float*>(&w4);
#pragma unroll
  for (int g = 0; g < 4; ++g) {
    float w, th;
    if (k < IN_) {
      w = Wx[(g * HID_ + j) * IN_ + k];
      th = thr[j * 8 + g];
    } else {
      w = Wh[(g * HID_ + j) * HID_ + (k - IN_)];
      th = thr[j * 8 + 4 + g];
    }
    float m = ((fabsf(w) - th) >= 0.0f) ? 1.0f : 0.0f;  // unit_step(|w|-thr)
    wp[g] = w * m;
  }
  reinterpret_cast<float4*>(W4)[idx] = w4;
}

// Transpose X[t][b][k] -> Xt[t][k][b]. Xt[t] is stored in out slice (t+1);
// Xt[T-1] goes to xlast (ws). Step t of the recurrent kernel reads slice t+1
// and writes H_t into slice t, so reads always precede any overwrite.
__global__ void transpose_x(const float* __restrict__ X,
                            float* __restrict__ out,
                            float* __restrict__ xlast) {
  __shared__ float tile[64][129];
  int t = blockIdx.x >> 2;
  int k0 = (blockIdx.x & 3) * 128;
  const float* src = X + (size_t)t * (BB * IN_) + k0;
#pragma unroll
  for (int j = 0; j < 8; ++j) {
    int f = threadIdx.x + j * 256;   // float4 index in 64x128 tile
    int b = f >> 5;                  // 32 float4 per row
    int m = (f & 31) * 4;
    float4 v = *reinterpret_cast<const float4*>(src + b * IN_ + m);
    tile[b][m + 0] = v.x; tile[b][m + 1] = v.y;
    tile[b][m + 2] = v.z; tile[b][m + 3] = v.w;
  }
  __syncthreads();
  float* dst = (t < TT - 1) ? (out + (size_t)(t + 1) * SLICE) : xlast;
  int b = threadIdx.x & 63;
  int ks = threadIdx.x >> 6;
#pragma unroll
  for (int u = 0; u < 32; ++u) {
    int kk = ks * 32 + u;
    dst[(k0 + kk) * BB + b] = tile[b][kk];  // lanes b consecutive: coalesced
  }
}

// Persistent cooperative LSTM. 256 blocks x 512 threads, 1 block/CU.
// Block owns h-pair {2*blk, 2*blk+1}. Weights (32 KB) live in LDS for the
// whole kernel — loaded ONCE (round-0 refetched them from HBM every step:
// 8.9 GB FETCH_SIZE, 98% stall). Inner loop: coalesced global activation
// load + broadcast (wave-uniform) ds_read_b128 weights + packed fp32 FMA.
__global__ void __launch_bounds__(512) lstm_rec(
    const float* __restrict__ W4, const float* __restrict__ bias,
    const float* __restrict__ h0p, const float* __restrict__ c0p,
    float* __restrict__ Hb0, float* __restrict__ Hb1,
    const float* __restrict__ xlast, float* __restrict__ out) {
  cg::grid_group grid = cg::this_grid();
  __shared__ float wlds[KTOT * 8];   // 32 KB: [k][h0:g0..3, h1:g0..3]
  __shared__ float red[8][64][9];    // pad 9: conflict-free strided reads
  const int tid = threadIdx.x;
  const int blk = blockIdx.x;
  const int b = tid & 63;
  const int ksub = __builtin_amdgcn_readfirstlane(tid >> 6);  // wave-uniform
  const int h0c = blk * 2;

  // One-time weight stage: global W4 float4 idx (k<<9)+h0c+{0,1} -> LDS.
  const float4* Wsrc = reinterpret_cast<const float4*>(W4);
  float4* Wdst = reinterpret_cast<float4*>(wlds);
  for (int i = tid; i < KTOT * 2; i += 512) {
    int k = i >> 1, r = i & 1;
    Wdst[k * 2 + r] = Wsrc[(k << 9) + h0c + r];
  }

  // Init: H_{-1} = h0 into Hb0 in [h][b] layout; C from c0.
  float C = 0.0f;
  if (tid < 128) {
    int hh = h0c + (tid >> 6);
    Hb0[hh * BB + b] = h0p[b * HID_ + hh];
    C = c0p[b * HID_ + hh];
  }
  __syncthreads();
  grid.sync();

  for (int t = 0; t < TT; ++t) {
    const float* Hprev = (t & 1) ? Hb1 : Hb0;
    float* Hnext = (t & 1) ? Hb0 : Hb1;
    const float* Xs = (t < TT - 1) ? (out + (size_t)(t + 1) * SLICE) : xlast;
    const int k0 = ksub * 128;
    const float* Abase = (ksub < 4) ? (Xs + k0 * BB + b)
                                    : (Hprev + (k0 - IN_) * BB + b);
    const float* wp = wlds + k0 * 8;

    v2f acc0 = {0.f, 0.f};  // h0: (i,f)
    v2f acc1 = {0.f, 0.f};  // h0: (o,c)
    v2f acc2 = {0.f, 0.f};  // h1: (i,f)
    v2f acc3 = {0.f, 0.f};  // h1: (o,c)
#pragma unroll 4
    for (int i = 0; i < 128; ++i) {
      float a = Abase[i * BB];  // lane-coalesced [k][b] global load (L2/L3)
      float4 wa = *reinterpret_cast<const float4*>(wp + i * 8);      // bcast
      float4 wb = *reinterpret_cast<const float4*>(wp + i * 8 + 4);  // bcast
      v2f av = {a, a};
      acc0 = __builtin_elementwise_fma((v2f){wa.x, wa.y}, av, acc0);
      acc1 = __builtin_elementwise_fma((v2f){wa.z, wa.w}, av, acc1);
      acc2 = __builtin_elementwise_fma((v2f){wb.x, wb.y}, av, acc2);
      acc3 = __builtin_elementwise_fma((v2f){wb.z, wb.w}, av, acc3);
    }
    float* rp = &red[ksub][b][0];
    rp[0] = acc0.x; rp[1] = acc0.y; rp[2] = acc1.x; rp[3] = acc1.y;
    rp[4] = acc2.x; rp[5] = acc2.y; rp[6] = acc3.x; rp[7] = acc3.y;
    __syncthreads();

    if (tid < 128) {
      int hsub = tid >> 6;
      int hh = h0c + hsub;
      float gs[4];
#pragma unroll
      for (int gg = 0; gg < 4; ++gg) {
        float s = bias[gg * HID_ + hh];
#pragma unroll
        for (int ks = 0; ks < 8; ++ks) s += red[ks][b][hsub * 4 + gg];
        gs[gg] = s;
      }
      float I = sigmoid_fast(gs[0]);
      float F = sigmoid_fast(gs[1]);
      float O = sigmoid_fast(gs[2]);
      float Ctl = tanh_fast(gs[3]);
      C = F * C + I * Ctl;
      float H = O * tanh_fast(C);
      out[(size_t)t * SLICE + b * HID_ + hh] = H;  // final output
      Hnext[hh * BB + b] = H;                      // [h][b] for next step
    }
    __threadfence();
    grid.sync();
  }
}

extern "C" void kernel_launch(void* const* d_in, const int* in_sizes, int n_in,
                              void* d_out, int out_size, void* d_ws, size_t ws_size,
                              hipStream_t stream) {
  (void)in_sizes; (void)n_in; (void)out_size; (void)ws_size;
  const float* X    = (const float*)d_in[0];
  const float* Wx   = (const float*)d_in[1];
  const float* Wh   = (const float*)d_in[2];
  const float* bias = (const float*)d_in[3];
  const float* thr  = (const float*)d_in[4];
  const float* h0p  = (const float*)d_in[5];
  const float* c0p  = (const float*)d_in[6];
  float* out = (float*)d_out;

  // ws layout (floats): W4 [1024][512][4] | Hb0 | Hb1 | xlast  (~8.8 MB)
  float* W4 = (float*)d_ws;
  float* Hb0 = W4 + (size_t)KTOT * HID_ * 4;
  float* Hb1 = Hb0 + SLICE;
  float* xlast = Hb1 + SLICE;

  prep_weights<<<(KTOT * HID_) / 256, 256, 0, stream>>>(Wx, Wh, thr, W4);
  transpose_x<<<TT * 4, 256, 0, stream>>>(X, out, xlast);

  void* args[] = {&W4, &bias, &h0p, &c0p, &Hb0, &Hb1, &xlast, &out};
  hipLaunchCooperativeKernel(reinterpret_cast<void*>(lstm_rec),
                             dim3(256), dim3(512), args, 0, stream);
}

// Round 3
// 11336.597 us; speedup vs baseline: 8.5329x; 7.6155x over previous
//
#include <hip/hip_runtime.h>

#define TT 1024
#define BB 64
#define IN_ 512
#define HID_ 512
#define KTOT 1024
#define SLICE (BB * HID_)  // 32768 floats, one [t] slice of out / one Xt slice

#define AGENT __HIP_MEMORY_SCOPE_AGENT

typedef float v2f __attribute__((ext_vector_type(2)));

__device__ __forceinline__ float sigmoid_fast(float x) {
  return 1.0f / (1.0f + __expf(-x));
}

__device__ __forceinline__ float tanh_fast(float x) {
  float ax = fabsf(x);
  float e = __expf(2.0f * ax);          // >= 1, inf-safe
  float r = 1.0f - 2.0f / (e + 1.0f);   // in [0,1)
  return copysignf(r, x);
}

// LLC-coherent (device-scope, relaxed) load/store: emits global_load/store
// with sc0 sc1 — bypasses the non-coherent per-XCD L2, NO cache flush needed.
__device__ __forceinline__ float ld_llc(const float* p) {
  return __hip_atomic_load(const_cast<float*>(p), __ATOMIC_RELAXED, AGENT);
}
__device__ __forceinline__ void st_llc(float* p, float v) {
  __hip_atomic_store(p, v, __ATOMIC_RELAXED, AGENT);
}

// Hand-rolled grid barrier: monotonic counter, relaxed agent atomics, no
// L2 writeback/invalidate (cg::grid.sync emits those every step on gfx950
// because per-XCD L2s are non-coherent — that was ~80 us/step).
// Ordering: the __syncthreads() before the arrive drains vmcnt(0), so all
// of this block's sc1 H-stores have reached the LLC before the add lands.
__device__ __forceinline__ void gridbar(unsigned* ctr, unsigned target) {
  __syncthreads();
  if (threadIdx.x == 0) {
    __hip_atomic_fetch_add(ctr, 1u, __ATOMIC_RELAXED, AGENT);
    while (__hip_atomic_load(ctr, __ATOMIC_RELAXED, AGENT) < target)
      __builtin_amdgcn_s_sleep(2);
  }
  __syncthreads();
}

// Build masked, transposed, gate-interleaved weights: W4[k][j][g]
__global__ void prep_weights(const float* __restrict__ Wx,
                             const float* __restrict__ Wh,
                             const float* __restrict__ thr,
                             float* __restrict__ W4, unsigned* __restrict__ ctr) {
  if (blockIdx.x == 0 && threadIdx.x == 0) *ctr = 0;  // barrier init (ws is poisoned)
  int idx = blockIdx.x * 256 + threadIdx.x;  // = k*512 + j
  int k = idx >> 9;
  int j = idx & 511;
  float4 w4;
  float* wp = reinterpret_cast<float*>(&w4);
#pragma unroll
  for (int g = 0; g < 4; ++g) {
    float w, th;
    if (k < IN_) {
      w = Wx[(g * HID_ + j) * IN_ + k];
      th = thr[j * 8 + g];
    } else {
      w = Wh[(g * HID_ + j) * HID_ + (k - IN_)];
      th = thr[j * 8 + 4 + g];
    }
    float m = ((fabsf(w) - th) >= 0.0f) ? 1.0f : 0.0f;  // unit_step(|w|-thr)
    wp[g] = w * m;
  }
  reinterpret_cast<float4*>(W4)[idx] = w4;
}

// Transpose X[t][b][k] -> Xt[t][k][b], stored in out slice (t+1); last to xlast.
__global__ void transpose_x(const float* __restrict__ X,
                            float* __restrict__ out,
                            float* __restrict__ xlast) {
  __shared__ float tile[64][129];
  int t = blockIdx.x >> 2;
  int k0 = (blockIdx.x & 3) * 128;
  const float* src = X + (size_t)t * (BB * IN_) + k0;
#pragma unroll
  for (int j = 0; j < 8; ++j) {
    int f = threadIdx.x + j * 256;   // float4 index in 64x128 tile
    int b = f >> 5;
    int m = (f & 31) * 4;
    float4 v = *reinterpret_cast<const float4*>(src + b * IN_ + m);
    tile[b][m + 0] = v.x; tile[b][m + 1] = v.y;
    tile[b][m + 2] = v.z; tile[b][m + 3] = v.w;
  }
  __syncthreads();
  float* dst = (t < TT - 1) ? (out + (size_t)(t + 1) * SLICE) : xlast;
  int b = threadIdx.x & 63;
  int ks = threadIdx.x >> 6;
#pragma unroll
  for (int u = 0; u < 32; ++u) {
    int kk = ks * 32 + u;
    dst[(k0 + kk) * BB + b] = tile[b][kk];
  }
}

// Persistent LSTM: 256 blocks x 512 threads, 1 block/CU, weights in LDS.
// Per step: X via normal L2-cached loads (read-only, never invalidated now),
// Hprev via sc1 LLC loads, barrier = relaxed-atomic counter.
__global__ void __launch_bounds__(512) lstm_rec(
    const float* __restrict__ W4, const float* __restrict__ bias,
    const float* __restrict__ h0p, const float* __restrict__ c0p,
    float* __restrict__ Hb0, float* __restrict__ Hb1,
    const float* __restrict__ xlast, float* __restrict__ out,
    unsigned* __restrict__ ctr) {
  __shared__ float wlds[KTOT * 8];   // 32 KB: [k][h0:g0..3, h1:g0..3]
  __shared__ float red[8][64][9];    // pad 9: conflict-free strided reads
  const int tid = threadIdx.x;
  const int blk = blockIdx.x;
  const int b = tid & 63;
  const int ksub = __builtin_amdgcn_readfirstlane(tid >> 6);  // wave-uniform
  const int h0c = blk * 2;
  unsigned bar_target = 256;

  // One-time weight stage into LDS.
  const float4* Wsrc = reinterpret_cast<const float4*>(W4);
  float4* Wdst = reinterpret_cast<float4*>(wlds);
  for (int i = tid; i < KTOT * 2; i += 512) {
    int k = i >> 1, r = i & 1;
    Wdst[k * 2 + r] = Wsrc[(k << 9) + h0c + r];
  }

  // Init: H_{-1} = h0 into Hb0 in [h][b] layout (LLC-coherent); C from c0.
  float C = 0.0f;
  if (tid < 128) {
    int hh = h0c + (tid >> 6);
    st_llc(&Hb0[hh * BB + b], h0p[b * HID_ + hh]);
    C = c0p[b * HID_ + hh];
  }
  gridbar(ctr, bar_target); bar_target += 256;

  for (int t = 0; t < TT; ++t) {
    const float* Hprev = (t & 1) ? Hb1 : Hb0;
    float* Hnext = (t & 1) ? Hb0 : Hb1;
    const float* Xs = (t < TT - 1) ? (out + (size_t)(t + 1) * SLICE) : xlast;
    const int k0 = ksub * 128;
    const float* wp = wlds + k0 * 8;

    v2f acc0 = {0.f, 0.f};  // h0: (i,f)
    v2f acc1 = {0.f, 0.f};  // h0: (o,c)
    v2f acc2 = {0.f, 0.f};  // h1: (i,f)
    v2f acc3 = {0.f, 0.f};  // h1: (o,c)
    if (ksub < 4) {
      const float* Abase = Xs + k0 * BB + b;     // normal cached loads
#pragma unroll 8
      for (int i = 0; i < 128; ++i) {
        float a = Abase[i * BB];
        float4 wa = *reinterpret_cast<const float4*>(wp + i * 8);
        float4 wb = *reinterpret_cast<const float4*>(wp + i * 8 + 4);
        v2f av = {a, a};
        acc0 = __builtin_elementwise_fma((v2f){wa.x, wa.y}, av, acc0);
        acc1 = __builtin_elementwise_fma((v2f){wa.z, wa.w}, av, acc1);
        acc2 = __builtin_elementwise_fma((v2f){wb.x, wb.y}, av, acc2);
        acc3 = __builtin_elementwise_fma((v2f){wb.z, wb.w}, av, acc3);
      }
    } else {
      const float* Abase = Hprev + (k0 - IN_) * BB + b;  // LLC-coherent loads
#pragma unroll 8
      for (int i = 0; i < 128; ++i) {
        float a = ld_llc(Abase + i * BB);
        float4 wa = *reinterpret_cast<const float4*>(wp + i * 8);
        float4 wb = *reinterpret_cast<const float4*>(wp + i * 8 + 4);
        v2f av = {a, a};
        acc0 = __builtin_elementwise_fma((v2f){wa.x, wa.y}, av, acc0);
        acc1 = __builtin_elementwise_fma((v2f){wa.z, wa.w}, av, acc1);
        acc2 = __builtin_elementwise_fma((v2f){wb.x, wb.y}, av, acc2);
        acc3 = __builtin_elementwise_fma((v2f){wb.z, wb.w}, av, acc3);
      }
    }
    float* rp = &red[ksub][b][0];
    rp[0] = acc0.x; rp[1] = acc0.y; rp[2] = acc1.x; rp[3] = acc1.y;
    rp[4] = acc2.x; rp[5] = acc2.y; rp[6] = acc3.x; rp[7] = acc3.y;
    __syncthreads();

    if (tid < 128) {
      int hsub = tid >> 6;
      int hh = h0c + hsub;
      float gs[4];
#pragma unroll
      for (int gg = 0; gg < 4; ++gg) {
        float s = bias[gg * HID_ + hh];
#pragma unroll
        for (int ks = 0; ks < 8; ++ks) s += red[ks][b][hsub * 4 + gg];
        gs[gg] = s;
      }
      float I = sigmoid_fast(gs[0]);
      float F = sigmoid_fast(gs[1]);
      float O = sigmoid_fast(gs[2]);
      float Ctl = tanh_fast(gs[3]);
      C = F * C + I * Ctl;
      float H = O * tanh_fast(C);
      out[(size_t)t * SLICE + b * HID_ + hh] = H;  // final output (normal store)
      st_llc(&Hnext[hh * BB + b], H);              // coherent H for next step
    }
    gridbar(ctr, bar_target); bar_target += 256;
  }
}

extern "C" void kernel_launch(void* const* d_in, const int* in_sizes, int n_in,
                              void* d_out, int out_size, void* d_ws, size_t ws_size,
                              hipStream_t stream) {
  (void)in_sizes; (void)n_in; (void)out_size; (void)ws_size;
  const float* X    = (const float*)d_in[0];
  const float* Wx   = (const float*)d_in[1];
  const float* Wh   = (const float*)d_in[2];
  const float* bias = (const float*)d_in[3];
  const float* thr  = (const float*)d_in[4];
  const float* h0p  = (const float*)d_in[5];
  const float* c0p  = (const float*)d_in[6];
  float* out = (float*)d_out;

  // ws layout (floats): W4 [1024][512][4] | Hb0 | Hb1 | xlast | ctr (~8.8 MB)
  float* W4 = (float*)d_ws;
  float* Hb0 = W4 + (size_t)KTOT * HID_ * 4;
  float* Hb1 = Hb0 + SLICE;
  float* xlast = Hb1 + SLICE;
  unsigned* ctr = (unsigned*)(xlast + SLICE);

  prep_weights<<<(KTOT * HID_) / 256, 256, 0, stream>>>(Wx, Wh, thr, W4, ctr);
  transpose_x<<<TT * 4, 256, 0, stream>>>(X, out, xlast);

  void* args[] = {&W4, &bias, &h0p, &c0p, &Hb0, &Hb1, &xlast, &out, &ctr};
  hipLaunchCooperativeKernel(reinterpret_cast<void*>(lstm_rec),
                             dim3(256), dim3(512), args, 0, stream);
}